// Round 11
// baseline (136.781 us; speedup 1.0000x reference)
//
#include <hip/hip_runtime.h>
#include <stdint.h>

typedef float f4_t __attribute__((ext_vector_type(4)));
typedef float f16_t __attribute__((ext_vector_type(16)));
typedef __bf16 bf8_t __attribute__((ext_vector_type(8)));
typedef unsigned short us4_t __attribute__((ext_vector_type(4)));
typedef unsigned short us8_t __attribute__((ext_vector_type(8)));

static __device__ __forceinline__ unsigned short fbf(float f) {
    __bf16 b = (__bf16)f;
    return *(unsigned short*)&b;
}
static __device__ __forceinline__ float bf2f(unsigned short u) {
    union { uint32_t u; float f; } v; v.u = ((uint32_t)u) << 16;
    return v.f;
}
static __device__ __forceinline__ f4_t mfma16(bf8_t a, bf8_t b, f4_t c) {
    return __builtin_amdgcn_mfma_f32_16x16x32_bf16(a, b, c, 0, 0, 0);
}
static __device__ __forceinline__ f16_t mfma32(bf8_t a, bf8_t b, f16_t c) {
    return __builtin_amdgcn_mfma_f32_32x32x16_bf16(a, b, c, 0, 0, 0);
}
static __device__ __forceinline__ float sigf(float x) {
    return 1.0f / (1.0f + __expf(-x));
}
static __device__ __forceinline__ void gload_lds16(const void* g, void* l) {
    __builtin_amdgcn_global_load_lds(
        (const __attribute__((address_space(1))) void*)g,
        (__attribute__((address_space(3))) void*)l, 16, 0, 0);
}
static __device__ __forceinline__ uint32_t cvtpk(float lo, float hi) {
    uint32_t r;
    asm("v_cvt_pk_bf16_f32 %0, %1, %2" : "=v"(r) : "v"(lo), "v"(hi));
    return r;
}

// ---------------- kernel 0: convert x/h/W to bf16, build q-normalized x ----
__global__ __launch_bounds__(256) void k_convert(
    const float* __restrict__ x, const float* __restrict__ h,
    const float* __restrict__ W1, const float* __restrict__ W2,
    unsigned short* __restrict__ qn, unsigned short* __restrict__ xb,
    unsigned short* __restrict__ hb, unsigned short* __restrict__ w1b,
    unsigned short* __restrict__ w2b)
{
    __shared__ float sred[4];
    int bid = blockIdx.x, t = threadIdx.x;
    if (bid < 256) {
        float v = x[bid * 256 + t];
        float ss = v * v;
        #pragma unroll
        for (int m = 1; m < 64; m <<= 1) ss += __shfl_xor(ss, m, 64);
        if ((t & 63) == 0) sred[t >> 6] = ss;
        __syncthreads();
        float tot = sred[0] + sred[1] + sred[2] + sred[3];
        float rn = 1.0f / fmaxf(sqrtf(tot), 1e-8f);
        xb[bid * 256 + t] = fbf(v);
        qn[bid * 256 + t] = fbf(v * rn);
    } else if (bid < 512) {
        int b = bid - 256;
        hb[b * 256 + t] = fbf(h[b * 256 + t]);
    } else {
        int i0 = (bid - 512) * 256 + t;
        for (int i = i0; i < 1280 * 256; i += 512 * 256) {
            w1b[i] = fbf(W1[i]);
            w2b[i] = fbf(W2[i]);
        }
    }
}

// ---------------- kernel 1: preact = x@W1^T + h@W2^T + b1 + b2 --------------
__global__ __launch_bounds__(256) void k_gates(
    const unsigned short* __restrict__ xb, const unsigned short* __restrict__ hb,
    const unsigned short* __restrict__ w1b, const unsigned short* __restrict__ w2b,
    const float* __restrict__ b1, const float* __restrict__ b2,
    float* __restrict__ pre)
{
    int bb = (blockIdx.x & 3) * 64;
    int gb = (blockIdx.x >> 2) * 64;
    int t = threadIdx.x, w = t >> 6, lane = t & 63;
    int l15 = lane & 15, q8 = (lane >> 4) * 8, q4 = (lane >> 4) * 4;
    int arow = bb + w * 16 + l15;

    f4_t acc[4] = {};
    #pragma unroll
    for (int ks = 0; ks < 8; ++ks) {
        bf8_t a = *(const bf8_t*)&xb[arow * 256 + ks * 32 + q8];
        #pragma unroll
        for (int gc = 0; gc < 4; ++gc) {
            bf8_t bf = *(const bf8_t*)&w1b[(gb + gc * 16 + l15) * 256 + ks * 32 + q8];
            acc[gc] = mfma16(a, bf, acc[gc]);
        }
    }
    #pragma unroll
    for (int ks = 0; ks < 8; ++ks) {
        bf8_t a = *(const bf8_t*)&hb[arow * 256 + ks * 32 + q8];
        #pragma unroll
        for (int gc = 0; gc < 4; ++gc) {
            bf8_t bf = *(const bf8_t*)&w2b[(gb + gc * 16 + l15) * 256 + ks * 32 + q8];
            acc[gc] = mfma16(a, bf, acc[gc]);
        }
    }
    #pragma unroll
    for (int gc = 0; gc < 4; ++gc) {
        int g = gb + gc * 16 + l15;
        float bias = b1[g] + b2[g];
        #pragma unroll
        for (int r = 0; r < 4; ++r) {
            int b = bb + w * 16 + q4 + r;
            pre[b * 1280 + g] = acc[gc][r] + bias;
        }
    }
}

// ---------------- kernel 2: fused DND memory partials ------------------------
// 512 blocks = 256 chunks x 2 h-halves (twins bid/bid^8 -> same XCD, K/V
// L2-shared). 512 threads = 8 waves; wave w owns b-rows w*32..+31 x 128 h.
// 32-key tiles. BOTH raw (fp32, DMA'd via global_load_lds) and converted
// (bf16) buffers double-buffered -> convert(t+1) runs IN THE SAME barrier-
// free region as GEMM(t): VALU convert overlaps MFMA (separate pipes).
// One counted vmcnt(6) + one barrier per tile; each wave DMAs AND converts
// only its own rows (no cross-wave raw hazard). 147KB LDS, 1 block/CU.
__global__ __launch_bounds__(512, 1) void k_dnd(
    const float* __restrict__ keys, const float* __restrict__ vals,
    const unsigned short* __restrict__ qn,
    unsigned short* __restrict__ opart, float* __restrict__ dpart,
    int L, int CH)
{
    // rawK[2] @0      : 2 x 32 x 1024B = 65536
    // rawV[2] @65536  : 2 x 32 x 512B  = 32768
    // Kb[2]   @98304  : 2 x 32 rows x 528B = 33792  (odd-16B stride)
    // Vb[2]   @132096 : 2 x 128 rows x 72B = 18432  (odd-8B stride)
    __shared__ __align__(16) char smem[150528];

    const int t = threadIdx.x;
    const int w = t >> 6, lane = t & 63;
    const int l31 = lane & 31, hi = lane >> 5;

    const int bid = blockIdx.x;
    const int hhalf = (bid >> 3) & 1;
    const int chunk = (bid & 7) | ((bid >> 4) << 3);
    const int base = chunk * CH;
    int nk = L - base;
    if (nk > CH) nk = CH;
    if (nk < 0) nk = 0;
    const int nt = (nk + 31) >> 5;

    // Q fragments: B-operand of swapped GEMM1 (col b = lane&31)
    bf8_t qf[16];
    #pragma unroll
    for (int st = 0; st < 16; ++st)
        qf[st] = *(const bf8_t*)&qn[(w * 32 + l31) * 256 + st * 16 + hi * 8];
    // resolve qf before any DMA so the compiler never needs a later vmcnt(0)
    asm volatile("s_waitcnt vmcnt(0)" ::: "memory");

    f16_t o[4] = {};
    float den = 0.f;

    // wave w DMAs raw K rows 4w..4w+3 and raw V rows 4w..4w+3 (its own)
    auto issueRaw = [&](int tt) {
        char* rK = smem + (tt & 1) * 32768;
        char* rV = smem + 65536 + (tt & 1) * 16384;
        int r0 = base + tt * 32;
        #pragma unroll
        for (int i = 0; i < 4; ++i) {
            int row = r0 + 4 * w + i;
            if (row >= L) row = L - 1;
            gload_lds16(keys + (size_t)row * 256 + lane * 4, rK + (4 * w + i) * 1024);
        }
        #pragma unroll
        for (int j = 0; j < 2; ++j) {
            int row = r0 + 4 * w + 2 * j + hi;
            if (row >= L) row = L - 1;
            gload_lds16(vals + (size_t)row * 256 + hhalf * 128 + l31 * 4,
                        rV + (4 * w + 2 * j) * 512);
        }
    };

    // wave w converts exactly its own raw rows -> bf16 buffers
    auto convert = [&](int tt) {
        const char* rK = smem + (tt & 1) * 32768;
        const char* rV = smem + 65536 + (tt & 1) * 16384;
        char* Kb = smem + 98304 + (tt & 1) * 16896;
        unsigned short* Vb = (unsigned short*)(smem + 132096 + (tt & 1) * 9216);
        // K: row r = t>>4 (wave-own), 16 thr/row, thread holds 16 floats
        {
            int r = t >> 4, j = t & 15;
            const char* rk = rK + r * 1024 + j * 64;
            f4_t x0 = *(const f4_t*)(rk);
            f4_t x1 = *(const f4_t*)(rk + 16);
            f4_t x2 = *(const f4_t*)(rk + 32);
            f4_t x3 = *(const f4_t*)(rk + 48);
            float ss = x0[0]*x0[0] + x0[1]*x0[1] + x0[2]*x0[2] + x0[3]*x0[3]
                     + x1[0]*x1[0] + x1[1]*x1[1] + x1[2]*x1[2] + x1[3]*x1[3]
                     + x2[0]*x2[0] + x2[1]*x2[1] + x2[2]*x2[2] + x2[3]*x2[3]
                     + x3[0]*x3[0] + x3[1]*x3[1] + x3[2]*x3[2] + x3[3]*x3[3];
            ss += __shfl_xor(ss, 1, 64);
            ss += __shfl_xor(ss, 2, 64);
            ss += __shfl_xor(ss, 4, 64);
            ss += __shfl_xor(ss, 8, 64);
            float rn = 1.0f / fmaxf(sqrtf(ss), 1e-8f);
            union { uint32_t u[4]; us8_t s; } p0, p1;
            p0.u[0] = cvtpk(x0[0]*rn, x0[1]*rn); p0.u[1] = cvtpk(x0[2]*rn, x0[3]*rn);
            p0.u[2] = cvtpk(x1[0]*rn, x1[1]*rn); p0.u[3] = cvtpk(x1[2]*rn, x1[3]*rn);
            p1.u[0] = cvtpk(x2[0]*rn, x2[1]*rn); p1.u[1] = cvtpk(x2[2]*rn, x2[3]*rn);
            p1.u[2] = cvtpk(x3[0]*rn, x3[1]*rn); p1.u[3] = cvtpk(x3[2]*rn, x3[3]*rn);
            *(us8_t*)(Kb + r * 528 + j * 32)      = p0.s;
            *(us8_t*)(Kb + r * 528 + j * 32 + 16) = p1.s;
        }
        // V: wave-own l-rows 4w..4w+3; thread covers h = lane, lane+64
        #pragma unroll
        for (int k = 0; k < 2; ++k) {
            int hh = lane + 64 * k;
            float v0 = *(const float*)(rV + (4 * w + 0) * 512 + hh * 4);
            float v1 = *(const float*)(rV + (4 * w + 1) * 512 + hh * 4);
            float v2 = *(const float*)(rV + (4 * w + 2) * 512 + hh * 4);
            float v3 = *(const float*)(rV + (4 * w + 3) * 512 + hh * 4);
            union { uint32_t u[2]; us4_t s; } pv;
            pv.u[0] = cvtpk(v0, v1);
            pv.u[1] = cvtpk(v2, v3);
            *(us4_t*)((char*)Vb + hh * 72 + 8 * w) = pv.s;
        }
    };

    if (nt > 0) {
        issueRaw(0);
        if (nt > 1) {
            issueRaw(1);
            asm volatile("s_waitcnt vmcnt(6)" ::: "memory");
        } else {
            asm volatile("s_waitcnt vmcnt(0)" ::: "memory");
        }
        convert(0);
        asm volatile("s_waitcnt lgkmcnt(0)\n\ts_barrier" ::: "memory");

        for (int tt = 0; tt < nt; ++tt) {
            // (a) issue raw(t+2); (b) counted wait for raw(t+1)
            if (tt + 2 < nt) {
                issueRaw(tt + 2);
                asm volatile("s_waitcnt vmcnt(6)" ::: "memory");
            } else {
                asm volatile("s_waitcnt vmcnt(0)" ::: "memory");
            }
            // (d1) convert(t+1) -- same region as GEMM(t): VALU || MFMA
            if (tt + 1 < nt) convert(tt + 1);

            const char* Kb = smem + 98304 + (tt & 1) * 16896;
            const char* Vb = smem + 132096 + (tt & 1) * 9216;

            // (d2) GEMM1 (swapped): S[l][b] = K @ Q^T
            f16_t sc = {};
            __builtin_amdgcn_s_setprio(1);
            #pragma unroll
            for (int st = 0; st < 16; ++st) {
                bf8_t kf = *(const bf8_t*)(Kb + l31 * 528 + st * 32 + hi * 16);
                sc = mfma32(kf, qf[st], sc);
            }
            __builtin_amdgcn_s_setprio(0);

            // softmax in-register: p = exp(s-1) (sims in [-1,1])
            float p[16];
            bool full = (tt * 32 + 32 <= nk);
            #pragma unroll
            for (int r = 0; r < 16; ++r) {
                int l = (r & 3) + 8 * (r >> 2) + 4 * hi;
                float pv = __expf(sc[r] - 1.0f);
                if (!full && (tt * 32 + l) >= nk) pv = 0.f;
                p[r] = pv;
                den += pv;
            }
            uint32_t a0 = cvtpk(p[0], p[1]),   a1 = cvtpk(p[2], p[3]);
            uint32_t b0 = cvtpk(p[4], p[5]),   b1 = cvtpk(p[6], p[7]);
            uint32_t c0 = cvtpk(p[8], p[9]),   c1 = cvtpk(p[10], p[11]);
            uint32_t d0 = cvtpk(p[12], p[13]), d1 = cvtpk(p[14], p[15]);
            asm("v_permlane32_swap_b32 %0, %1" : "+v"(a0), "+v"(b0));
            asm("v_permlane32_swap_b32 %0, %1" : "+v"(a1), "+v"(b1));
            asm("v_permlane32_swap_b32 %0, %1" : "+v"(c0), "+v"(d0));
            asm("v_permlane32_swap_b32 %0, %1" : "+v"(c1), "+v"(d1));
            union { uint32_t u[4]; bf8_t v; } pa0, pa1;
            pa0.u[0] = a0; pa0.u[1] = a1; pa0.u[2] = b0; pa0.u[3] = b1;
            pa1.u[0] = c0; pa1.u[1] = c1; pa1.u[2] = d0; pa1.u[3] = d1;

            // GEMM2: O[b][h] += P @ V
            __builtin_amdgcn_s_setprio(1);
            #pragma unroll
            for (int g = 0; g < 4; ++g) {
                bf8_t vf0 = *(const bf8_t*)(Vb + (g * 32 + l31) * 72 + hi * 16);
                bf8_t vf1 = *(const bf8_t*)(Vb + (g * 32 + l31) * 72 + 32 + hi * 16);
                o[g] = mfma32(pa0.v, vf0, o[g]);
                o[g] = mfma32(pa1.v, vf1, o[g]);
            }
            __builtin_amdgcn_s_setprio(0);

            // (e) one barrier per tile
            asm volatile("s_waitcnt lgkmcnt(0)\n\ts_barrier" ::: "memory");
        }
    }

    // ---- epilogue: LDS transpose -> coalesced stores; den combine ----
    __syncthreads();
    unsigned short* Ol = (unsigned short*)smem;   // [256 b][128 h]
    #pragma unroll
    for (int g = 0; g < 4; ++g)
        #pragma unroll
        for (int r = 0; r < 16; ++r) {
            int b = w * 32 + (r & 3) + 8 * (r >> 2) + 4 * hi;
            Ol[b * 128 + g * 32 + l31] = fbf(o[g][r]);
        }
    __syncthreads();
    {
        size_t ob = (size_t)(chunk * 2 + hhalf) * 32768;
        #pragma unroll
        for (int it = 0; it < 8; ++it) {
            int off = it * 4096 + t * 8;
            *(us8_t*)&opart[ob + off] = *(const us8_t*)&Ol[off];
        }
    }
    den += __shfl_xor(den, 32, 64);
    if (hi == 0 && hhalf == 0)
        dpart[chunk * 256 + w * 32 + l31] = den;
}

// ---------------- kernel 3: reduce partials + LSTM epilogue -----------------
__global__ __launch_bounds__(256) void k_reduce(
    const unsigned short* __restrict__ opart, const float* __restrict__ dpart,
    const float* __restrict__ pre, const float* __restrict__ c_in,
    float* __restrict__ out)
{
    __shared__ float sred[4];
    int b = blockIdx.x, t = threadIdx.x;

    float ds = dpart[t * 256 + b];
    #pragma unroll
    for (int m = 1; m < 64; m <<= 1) ds += __shfl_xor(ds, m, 64);
    if ((t & 63) == 0) sred[t >> 6] = ds;
    __syncthreads();
    float dtot = fmaxf(sred[0] + sred[1] + sred[2] + sred[3], 1e-30f);

    int hh = t >> 7, hc = t & 127;
    size_t sb = (size_t)b * 128 + hc;
    float n0 = 0.f, n1 = 0.f, n2 = 0.f, n3 = 0.f;
    for (int ck = 0; ck < 256; ck += 4) {
        n0 += bf2f(opart[(size_t)((ck + 0) * 2 + hh) * 32768 + sb]);
        n1 += bf2f(opart[(size_t)((ck + 1) * 2 + hh) * 32768 + sb]);
        n2 += bf2f(opart[(size_t)((ck + 2) * 2 + hh) * 32768 + sb]);
        n3 += bf2f(opart[(size_t)((ck + 3) * 2 + hh) * 32768 + sb]);
    }
    float num = (n0 + n1) + (n2 + n3);

    float m = tanhf(num / dtot);
    const float* p = pre + b * 1280;
    float fg = sigf(p[t]);
    float ig = sigf(p[256 + t]);
    float og = sigf(p[512 + t]);
    float rg = sigf(p[768 + t]);
    float cn = tanhf(p[1024 + t]);
    float co = c_in[b * 256 + t];
    float ct = fg * co + ig * cn + rg * m;
    float ht = og * tanhf(ct);
    out[b * 256 + t] = ht;
    out[65536 + b * 256 + t] = ct;
}

// ---------------- launch ----------------------------------------------------
extern "C" void kernel_launch(void* const* d_in, const int* in_sizes, int n_in,
                              void* d_out, int out_size, void* d_ws, size_t ws_size,
                              hipStream_t stream)
{
    const float* x    = (const float*)d_in[0];
    const float* h    = (const float*)d_in[1];
    const float* c    = (const float*)d_in[2];
    const float* W1   = (const float*)d_in[3];
    const float* b1   = (const float*)d_in[4];
    const float* W2   = (const float*)d_in[5];
    const float* b2   = (const float*)d_in[6];
    const float* keys = (const float*)d_in[7];
    const float* vals = (const float*)d_in[8];
    int L = in_sizes[7] / 256;

    // 256 chunks, each a multiple of 32 keys
    int TILES = (L + 256 * 32 - 1) / (256 * 32);
    int CH = TILES * 32;

    char* ws = (char*)d_ws;
    unsigned short* qn    = (unsigned short*)(ws + 0);
    unsigned short* xb    = (unsigned short*)(ws + 131072);
    unsigned short* hb    = (unsigned short*)(ws + 262144);
    unsigned short* w1b   = (unsigned short*)(ws + 393216);
    unsigned short* w2b   = (unsigned short*)(ws + 1048576);
    float*          pre   = (float*)(ws + 1703936);
    float*          dpart = (float*)(ws + 3014656);   // 256*256 f32 = 256KB
    unsigned short* opart = (unsigned short*)(ws + 3276800);  // 512*32768*2B

    k_convert<<<dim3(1024), dim3(256), 0, stream>>>(x, h, W1, W2, qn, xb, hb, w1b, w2b);
    k_gates<<<dim3(80), dim3(256), 0, stream>>>(xb, hb, w1b, w2b, b1, b2, pre);
    k_dnd<<<dim3(512), dim3(512), 0, stream>>>(keys, vals, qn, opart, dpart, L, CH);
    k_reduce<<<dim3(256), dim3(256), 0, stream>>>(opart, dpart, pre, c, (float*)d_out);

    (void)n_in; (void)out_size; (void)ws_size;
}